// Round 4
// baseline (329.016 us; speedup 1.0000x reference)
//
#include <hip/hip_runtime.h>

typedef __bf16 bf16;
using short8 = __attribute__((ext_vector_type(8))) short;
using f32x4  = __attribute__((ext_vector_type(4))) float;

#define N_TOK 4128
#define N_PAD 4160
#define QD    320
#define DH    40
#define W_VIS 4096
#define SPLITS 4

__device__ __forceinline__ float loadS(const void* b, long i, bool isbf) {
  return isbf ? (float)((const bf16*)b)[i] : ((const float*)b)[i];
}

// DPP cross-lane (VALU pipe, no LDS): reduction over the 16-lane "row"
template <int C>
__device__ __forceinline__ float dppmov(float x) {
  return __builtin_bit_cast(float, __builtin_amdgcn_update_dpp(
      0, __builtin_bit_cast(int, x), C, 0xF, 0xF, true));
}
__device__ __forceinline__ float max16(float v) {
  v = fmaxf(v, dppmov<0xB1>(v));    // quad_perm [1,0,3,2]  (xor 1)
  v = fmaxf(v, dppmov<0x4E>(v));    // quad_perm [2,3,0,1]  (xor 2)
  v = fmaxf(v, dppmov<0x124>(v));   // row_ror:4
  v = fmaxf(v, dppmov<0x128>(v));   // row_ror:8
  return v;
}

// ---------- dtype sniffer: att_masks is exactly {0,1}; fp32 -> even halfwords all 0 ----------
__global__ __launch_bounds__(256) void sniff_kernel(const unsigned short* att_h, int* flag) {
  __shared__ int s;
  if (threadIdx.x == 0) s = 0;
  __syncthreads();
  int any = 0;
  for (int i = threadIdx.x; i < 4096; i += 256) any |= (att_h[2 * i] != 0);
  if (any) atomicOr(&s, 1);
  __syncthreads();
  if (threadIdx.x == 0) flag[0] = s;   // 1 = bf16 inputs, 0 = fp32 inputs
}

// ---------- prep: weight transposes, x->bf16, maskAB words, V-ones row ----------
__global__ __launch_bounds__(256) void prep_kernel(
    const void* __restrict__ x, const void* __restrict__ att,
    const void* __restrict__ Wq, const void* __restrict__ Wk,
    const void* __restrict__ Wv, const void* __restrict__ Wo,
    bf16* __restrict__ Wqt, bf16* __restrict__ Wkt,
    bf16* __restrict__ Wvt, bf16* __restrict__ Wot,
    bf16* __restrict__ xbf, unsigned int* __restrict__ mab,
    bf16* __restrict__ vt, const int* __restrict__ flag) {
  bool isbf = flag[0] != 0;
  int id = blockIdx.x * 256 + threadIdx.x;
  if (id < 409600) {                       // 4 weight transposes [k][n] -> [n][k]
    int wsel = id / 102400;
    int r = id % 102400;
    int k = r / 320, n = r % 320;
    const void* src = wsel == 0 ? Wq : wsel == 1 ? Wk : wsel == 2 ? Wv : Wo;
    bf16* dst       = wsel == 0 ? Wqt : wsel == 1 ? Wkt : wsel == 2 ? Wvt : Wot;
    dst[n * 320 + k] = (bf16)loadS(src, k * 320 + n, isbf);
  } else if (id < 409600 + 1320960) {      // x -> bf16
    int i = id - 409600;
    xbf[i] = (bf16)loadS(x, i, isbf);
  } else if (id < 409600 + 1320960 + N_PAD) {   // mask words: keep(i,j) = (A[i]&B[j])!=0
    int t = id - (409600 + 1320960);
    unsigned int Aw = 0u, Bw = 0u;
    if (t < N_TOK) {
      unsigned int b9 = 0u; bool forced = false;
      if (t < W_VIS) {
#pragma unroll
        for (int o = 0; o < 8; ++o)
          if (loadS(att, o * W_VIS + t, isbf) != 0.0f) b9 |= (1u << o);
      } else {
        int g = t - W_VIS;
        int rep = g >> 3, oo = g & 7;
        forced = (rep == 1 || rep == 2);
        b9 = 0x100u | (forced ? 0u : (1u << oo));
      }
      Aw = b9 | (forced ? 0x200u : 0u) | 0x400u;   // rows see all forced cols (0x400)
      Bw = b9 | (forced ? 0x400u : 0u) | 0x200u;   // cols see all forced rows (0x200)
    }
    mab[t] = Aw | (Bw << 16);
  } else {                                  // vt row d=40 := 1.0 (l-via-MFMA trick)
    int t = id - (409600 + 1320960 + N_PAD);
    if (t < 8 * N_TOK) {
      int h = t / N_TOK, tok = t % N_TOK;
      vt[h * (48 * N_TOK) + 40 * N_TOK + tok] = (bf16)1.0f;
    }
  }
}

// ---------- fused QKV GEMM: C = xbf[4128x320] * Bt^T; q pre-scaled by scale*log2(e) ----------
__global__ __launch_bounds__(256) void gemm_qkv(
    const bf16* __restrict__ A,
    const bf16* __restrict__ Bq, const bf16* __restrict__ Bk, const bf16* __restrict__ Bv,
    bf16* __restrict__ q, bf16* __restrict__ k, bf16* __restrict__ vt) {
  const float qscale = 0.15811388300841898f * 1.4426950408889634f;
  int m0 = blockIdx.x * 64;
  int ng = blockIdx.y * 64;
  int wsel = ng / 320;                 // 0=q 1=k 2=v
  int n_in = ng % 320;
  const bf16* Bt = wsel == 0 ? Bq : wsel == 1 ? Bk : Bv;
  int wv = threadIdx.x >> 6, lane = threadIdx.x & 63;
  int quad = lane >> 4, li = lane & 15;
  int wm = wv >> 1, wn = wv & 1;
  f32x4 acc[2][2];
#pragma unroll
  for (int a = 0; a < 2; a++)
#pragma unroll
    for (int b = 0; b < 2; b++) acc[a][b] = (f32x4){0.f, 0.f, 0.f, 0.f};
#pragma unroll
  for (int ks = 0; ks < 10; ++ks) {
    short8 af[2], bfrag[2];
#pragma unroll
    for (int mt = 0; mt < 2; ++mt) {
      int r = m0 + wm * 32 + mt * 16 + li;
      r = r < N_TOK ? r : N_TOK - 1;
      af[mt] = *(const short8*)(A + r * QD + ks * 32 + quad * 8);
    }
#pragma unroll
    for (int nt = 0; nt < 2; ++nt) {
      int r = n_in + wn * 32 + nt * 16 + li;
      bfrag[nt] = *(const short8*)(Bt + r * QD + ks * 32 + quad * 8);
    }
#pragma unroll
    for (int mt = 0; mt < 2; ++mt)
#pragma unroll
      for (int nt = 0; nt < 2; ++nt)
        acc[mt][nt] = __builtin_amdgcn_mfma_f32_16x16x32_bf16(af[mt], bfrag[nt], acc[mt][nt], 0, 0, 0);
  }
#pragma unroll
  for (int mt = 0; mt < 2; ++mt)
#pragma unroll
    for (int nt = 0; nt < 2; ++nt)
#pragma unroll
      for (int r = 0; r < 4; ++r) {
        int row = m0 + wm * 32 + mt * 16 + quad * 4 + r;
        if (row >= N_TOK) continue;
        int col = n_in + wn * 32 + nt * 16 + li;
        int h = col / DH, d = col % DH;
        float v = acc[mt][nt][r];
        if (wsel == 2) {
          vt[h * (48 * N_TOK) + d * N_TOK + row] = (bf16)v;
        } else if (wsel == 0) {
          q[h * (N_TOK * DH) + row * DH + d] = (bf16)(v * qscale);
        } else {
          k[h * (N_TOK * DH) + row * DH + d] = (bf16)v;
        }
      }
}

// ---------- split-K flash attention: partials (o, m, l) per (split, head, row) ----------
__global__ __launch_bounds__(256, 6) void attn_kernel(
    const bf16* __restrict__ q, const bf16* __restrict__ kk, const bf16* __restrict__ vt,
    const unsigned int* __restrict__ mab,
    float* __restrict__ opart, float* __restrict__ mpart, float* __restrict__ lpart) {
  __shared__ unsigned short pbuf[4][16][68];   // per-wave P tile; 68-stride = conflict-free
  int bid = blockIdx.x;
  int h = bid & 7;                 // head fastest -> per-head K/V pins to one XCD L2
  int sp = (bid >> 3) & 3;
  int qt = bid >> 5;               // 0..64
  int kt0 = (sp * 65) >> 2;
  int kt1 = ((sp + 1) * 65) >> 2;
  int qbase = qt * 64;
  int wv = threadIdx.x >> 6, lane = threadIdx.x & 63;
  int quad = lane >> 4, li = lane & 15;
  const bf16* qh = q + h * (N_TOK * DH);
  const bf16* kh = kk + h * (N_TOK * DH);
  const bf16* vth = vt + h * (48 * N_TOK);

  int qrow_base = qbase + wv * 16;
  int qr = qrow_base + li; if (qr > N_TOK - 1) qr = N_TOK - 1;
  short8 qa0 = *(const short8*)(qh + qr * DH + quad * 8);
  short8 qa1 = (quad == 0) ? *(const short8*)(qh + qr * DH + 32) : (short8)0;

  unsigned int aw[4]; int qi[4];
#pragma unroll
  for (int r = 0; r < 4; ++r) {
    qi[r] = qrow_base + quad * 4 + r;
    aw[r] = mab[qi[r]] & 0xFFFFu;
  }

  f32x4 o[3];
#pragma unroll
  for (int d = 0; d < 3; ++d) o[d] = (f32x4){0.f, 0.f, 0.f, 0.f};
  float mr[4] = {-30000.f, -30000.f, -30000.f, -30000.f};

  for (int kt = kt0; kt < kt1; ++kt) {
    int j0 = kt * 64;
    f32x4 sv[4];
    unsigned int bw[4]; int kj[4];
#pragma unroll
    for (int nt = 0; nt < 4; ++nt) {
      kj[nt] = j0 + nt * 16 + li;
      bw[nt] = mab[kj[nt]] >> 16;
      int krow = kj[nt] > N_TOK - 1 ? N_TOK - 1 : kj[nt];
      short8 kb0 = *(const short8*)(kh + krow * DH + quad * 8);
      sv[nt] = __builtin_amdgcn_mfma_f32_16x16x32_bf16(qa0, kb0, (f32x4){0.f, 0.f, 0.f, 0.f}, 0, 0, 0);
      short8 kb1 = (quad == 0) ? *(const short8*)(kh + krow * DH + 32) : (short8)0;
      sv[nt] = __builtin_amdgcn_mfma_f32_16x16x32_bf16(qa1, kb1, sv[nt], 0, 0, 0);
    }
    float t[4][4];
    if (kt == qt) {      // diagonal tile: epsilon-diag keeps i==j
#pragma unroll
      for (int nt = 0; nt < 4; ++nt)
#pragma unroll
        for (int r = 0; r < 4; ++r) {
          bool kp = ((aw[r] & bw[nt]) != 0u) || (qi[r] == kj[nt]);
          t[nt][r] = kp ? sv[nt][r] : -40000.f;
        }
    } else {
#pragma unroll
      for (int nt = 0; nt < 4; ++nt)
#pragma unroll
        for (int r = 0; r < 4; ++r) {
          bool kp = (aw[r] & bw[nt]) != 0u;
          t[nt][r] = kp ? sv[nt][r] : -40000.f;
        }
    }
    float mt4[4];
#pragma unroll
    for (int r = 0; r < 4; ++r)
      mt4[r] = max16(fmaxf(fmaxf(t[0][r], t[1][r]), fmaxf(t[2][r], t[3][r])));
    unsigned long long nb = __ballot(mt4[0] > mr[0] || mt4[1] > mr[1] ||
                                     mt4[2] > mr[2] || mt4[3] > mr[3]);
    if (nb) {            // rescale only when some row's max grew
#pragma unroll
      for (int r = 0; r < 4; ++r) {
        float mn = fmaxf(mr[r], mt4[r]);
        float al = exp2f(mr[r] - mn);
        mr[r] = mn;
#pragma unroll
        for (int d = 0; d < 3; ++d) o[d][r] *= al;
      }
    }
#pragma unroll
    for (int nt = 0; nt < 4; ++nt)
#pragma unroll
      for (int r = 0; r < 4; ++r) {
        float p = exp2f(t[nt][r] - mr[r]);   // arg <= 0 structurally
        bf16 pb = (bf16)p;
        pbuf[wv][quad * 4 + r][nt * 16 + li] = __builtin_bit_cast(unsigned short, pb);
      }
    // PV: P (A-layout from own wave's LDS region) x Vt (B frags from global).
    // V row d=40 is all-ones -> o[2] col d=40 accumulates l for free.
#pragma unroll
    for (int ksv = 0; ksv < 2; ++ksv) {
      union { short8 v; ushort4 u[2]; } fp;
      fp.u[0] = *(const ushort4*)&pbuf[wv][li][ksv * 32 + quad * 8];
      fp.u[1] = *(const ushort4*)&pbuf[wv][li][ksv * 32 + quad * 8 + 4];
      int jj = j0 + ksv * 32 + quad * 8;
      if (jj > N_TOK - 8) jj = N_TOK - 8;    // clamped cols have P=0
#pragma unroll
      for (int dt = 0; dt < 3; ++dt) {
        short8 vb = *(const short8*)(vth + (dt * 16 + li) * N_TOK + jj);
        o[dt] = __builtin_amdgcn_mfma_f32_16x16x32_bf16(fp.v, vb, o[dt], 0, 0, 0);
      }
    }
  }
  int pb = (sp * 8 + h) * N_PAD;
#pragma unroll
  for (int dt = 0; dt < 3; ++dt) {
    int d = dt * 16 + li;
    if (d < DH) {
#pragma unroll
      for (int r = 0; r < 4; ++r)
        opart[(long)(pb + qi[r]) * DH + d] = o[dt][r];
    }
  }
  if (li == 0) {
#pragma unroll
    for (int r = 0; r < 4; ++r) mpart[pb + qi[r]] = mr[r];
  }
  if (li == 8) {         // d=40 (ones column) of dt=2 accumulator = l
#pragma unroll
    for (int r = 0; r < 4; ++r) lpart[pb + qi[r]] = o[2][r];
  }
}

// ---------- combine partials across splits ----------
__global__ __launch_bounds__(256) void combine_kernel(
    const float* __restrict__ opart, const float* __restrict__ mpart,
    const float* __restrict__ lpart, bf16* __restrict__ attn) {
  int id = blockIdx.x * 256 + threadIdx.x;
  if (id >= 8 * N_TOK * DH) return;
  int d = id % DH;
  int rw = (id / DH) % N_TOK;
  int h = id / (DH * N_TOK);
  float ms[SPLITS], M = -1e30f;
#pragma unroll
  for (int s = 0; s < SPLITS; ++s) {
    ms[s] = mpart[(s * 8 + h) * N_PAD + rw];
    M = fmaxf(M, ms[s]);
  }
  float osum = 0.f, lsum = 0.f;
#pragma unroll
  for (int s = 0; s < SPLITS; ++s) {
    float w = exp2f(ms[s] - M);
    osum += w * opart[(long)((s * 8 + h) * N_PAD + rw) * DH + d];
    lsum += w * lpart[(s * 8 + h) * N_PAD + rw];
  }
  attn[rw * QD + h * DH + d] = (bf16)(osum / fmaxf(lsum, 1e-30f));
}

// ---------- output projection + bias (dtype-aware bias read + final store) ----------
__global__ __launch_bounds__(256) void gemm_out(
    const bf16* __restrict__ A, const bf16* __restrict__ Bt,
    const void* __restrict__ bias, void* __restrict__ out,
    const int* __restrict__ flag) {
  bool isbf = flag[0] != 0;
  int m0 = blockIdx.x * 64;
  int n0 = blockIdx.y * 64;
  int wv = threadIdx.x >> 6, lane = threadIdx.x & 63;
  int quad = lane >> 4, li = lane & 15;
  int wm = wv >> 1, wn = wv & 1;
  f32x4 acc[2][2];
#pragma unroll
  for (int a = 0; a < 2; a++)
#pragma unroll
    for (int b = 0; b < 2; b++) acc[a][b] = (f32x4){0.f, 0.f, 0.f, 0.f};
#pragma unroll
  for (int ks = 0; ks < 10; ++ks) {
    short8 af[2], bfrag[2];
#pragma unroll
    for (int mt = 0; mt < 2; ++mt) {
      int r = m0 + wm * 32 + mt * 16 + li;
      r = r < N_TOK ? r : N_TOK - 1;
      af[mt] = *(const short8*)(A + r * QD + ks * 32 + quad * 8);
    }
#pragma unroll
    for (int nt = 0; nt < 2; ++nt) {
      int r = n0 + wn * 32 + nt * 16 + li;
      bfrag[nt] = *(const short8*)(Bt + r * QD + ks * 32 + quad * 8);
    }
#pragma unroll
    for (int mt = 0; mt < 2; ++mt)
#pragma unroll
      for (int nt = 0; nt < 2; ++nt)
        acc[mt][nt] = __builtin_amdgcn_mfma_f32_16x16x32_bf16(af[mt], bfrag[nt], acc[mt][nt], 0, 0, 0);
  }
#pragma unroll
  for (int mt = 0; mt < 2; ++mt)
#pragma unroll
    for (int nt = 0; nt < 2; ++nt)
#pragma unroll
      for (int r = 0; r < 4; ++r) {
        int row = m0 + wm * 32 + mt * 16 + quad * 4 + r;
        if (row >= N_TOK) continue;
        int col = n0 + wn * 32 + nt * 16 + li;
        float val = acc[mt][nt][r] + loadS(bias, col, isbf);
        if (isbf) ((bf16*)out)[row * QD + col] = (bf16)val;
        else      ((float*)out)[row * QD + col] = val;
      }
}

extern "C" void kernel_launch(void* const* d_in, const int* in_sizes, int n_in,
                              void* d_out, int out_size, void* d_ws, size_t ws_size,
                              hipStream_t stream) {
  (void)in_sizes; (void)n_in; (void)out_size; (void)ws_size;
  const void* x   = d_in[0];
  const void* att = d_in[1];
  const void* Wq  = d_in[2];
  const void* Wk  = d_in[3];
  const void* Wv  = d_in[4];
  const void* Wo  = d_in[5];
  const void* bo  = d_in[6];
  char* ws = (char*)d_ws;
  bf16* Wqt = (bf16*)(ws + 0);
  bf16* Wkt = (bf16*)(ws + 204800);
  bf16* Wvt = (bf16*)(ws + 409600);
  bf16* Wot = (bf16*)(ws + 614400);
  unsigned int* mab = (unsigned int*)(ws + 819200);        // 16640 -> 835840
  bf16* xbf  = (bf16*)(ws + 835840);                       // 2641920 -> 3477760
  bf16* qb   = (bf16*)(ws + 3477760);                      // 2641920 -> 6119680
  bf16* kb   = (bf16*)(ws + 6119680);                      // 2641920 -> 8761600
  bf16* vt   = (bf16*)(ws + 8761600);                      // 3170304 -> 11931904
  bf16* attn = (bf16*)(ws + 11931904);                     // 2641920 -> 14573824
  int* flag  = (int*)(ws + 14573824);
  float* opart = (float*)(ws + 14574080);                  // 21299200 -> 35873280
  float* mpart = (float*)(ws + 35873280);                  // 532480 -> 36405760
  float* lpart = (float*)(ws + 36405760);                  // 532480 -> 36938240

  hipMemsetAsync(vt, 0, 3170304, stream);  // zero V pad rows (prep sets d=40 to ones after)
  sniff_kernel<<<1, 256, 0, stream>>>((const unsigned short*)att, flag);
  prep_kernel<<<6906, 256, 0, stream>>>(x, att, Wq, Wk, Wv, Wo,
                                        Wqt, Wkt, Wvt, Wot, xbf, mab, vt, flag);
  dim3 g1(65, 15);
  gemm_qkv<<<g1, 256, 0, stream>>>(xbf, Wqt, Wkt, Wvt, qb, kb, vt);
  attn_kernel<<<65 * SPLITS * 8, 256, 0, stream>>>(qb, kb, vt, mab, opart, mpart, lpart);
  combine_kernel<<<(8 * N_TOK * DH + 255) / 256, 256, 0, stream>>>(opart, mpart, lpart, attn);
  dim3 g2(65, 5);
  gemm_out<<<g2, 256, 0, stream>>>(attn, Wot, bo, d_out, flag);
}

// Round 5
// 264.035 us; speedup vs baseline: 1.2461x; 1.2461x over previous
//
#include <hip/hip_runtime.h>

typedef __bf16 bf16;
using short8 = __attribute__((ext_vector_type(8))) __bf16;
using f32x4  = __attribute__((ext_vector_type(4))) float;

#define N_TOK 4128
#define QD    320
#define DH    40
#define W_VIS 4096
#define SPLITS 4
#define N_SP  4224   /* padded row count for partials / mask words (33*128) */

__device__ __forceinline__ float loadS(const void* b, long i, bool isbf) {
  return isbf ? (float)((const bf16*)b)[i] : ((const float*)b)[i];
}

// DPP cross-lane max over the 16-lane row group (VALU pipe, no LDS)
template <int C>
__device__ __forceinline__ float dppmov(float x) {
  return __builtin_bit_cast(float, __builtin_amdgcn_update_dpp(
      0, __builtin_bit_cast(int, x), C, 0xF, 0xF, true));
}
__device__ __forceinline__ float max16(float v) {
  v = fmaxf(v, dppmov<0xB1>(v));    // quad_perm xor1
  v = fmaxf(v, dppmov<0x4E>(v));    // quad_perm xor2
  v = fmaxf(v, dppmov<0x124>(v));   // row_ror:4
  v = fmaxf(v, dppmov<0x128>(v));   // row_ror:8
  return v;
}

// ---------- dtype sniffer: att_masks is {0,1}; fp32 -> even halfwords all 0 ----------
__global__ __launch_bounds__(256) void sniff_kernel(const unsigned short* att_h, int* flag) {
  __shared__ int s;
  if (threadIdx.x == 0) s = 0;
  __syncthreads();
  int any = 0;
  for (int i = threadIdx.x; i < 4096; i += 256) any |= (att_h[2 * i] != 0);
  if (any) atomicOr(&s, 1);
  __syncthreads();
  if (threadIdx.x == 0) flag[0] = s;
}

// ---------- prep: weight transposes (x4 vec), x->bf16 (x4), mask words, V ones-row ----------
#define SEG_A 102400             /* 409600 weight elems / 4 */
#define SEG_B 330240             /* 1320960 x elems / 4 */
#define SEG_C N_SP               /* mask words */
#define SEG_D 33280              /* vswz ones row: 8h*65kt*2ksv*4q*8li */
__global__ __launch_bounds__(256) void prep_kernel(
    const void* __restrict__ x, const void* __restrict__ att,
    const void* __restrict__ Wq, const void* __restrict__ Wk,
    const void* __restrict__ Wv, const void* __restrict__ Wo,
    bf16* __restrict__ Wqt, bf16* __restrict__ Wkt,
    bf16* __restrict__ Wvt, bf16* __restrict__ Wot,
    bf16* __restrict__ xbf, unsigned int* __restrict__ mab,
    bf16* __restrict__ vswz, const int* __restrict__ flag) {
  bool isbf = flag[0] != 0;
  int id = blockIdx.x * 256 + threadIdx.x;
  if (id < SEG_A) {                         // weight transpose, 4 n per thread
    int wsel = id / 25600;
    int r = id % 25600;
    int k = r / 80, n4 = (r % 80) * 4;
    const void* src = wsel == 0 ? Wq : wsel == 1 ? Wk : wsel == 2 ? Wv : Wo;
    bf16* dst       = wsel == 0 ? Wqt : wsel == 1 ? Wkt : wsel == 2 ? Wvt : Wot;
#pragma unroll
    for (int i = 0; i < 4; ++i)
      dst[(n4 + i) * 320 + k] = (bf16)loadS(src, k * 320 + n4 + i, isbf);
  } else if (id < SEG_A + SEG_B) {          // x -> bf16, 4 elems
    int i4 = (id - SEG_A) * 4;
#pragma unroll
    for (int i = 0; i < 4; ++i) xbf[i4 + i] = (bf16)loadS(x, i4 + i, isbf);
  } else if (id < SEG_A + SEG_B + SEG_C) {  // mask words: keep(i,j)=(A[i]&B[j])!=0
    int t = id - (SEG_A + SEG_B);
    unsigned int Aw = 0u, Bw = 0u;
    if (t < N_TOK) {
      unsigned int b9 = 0u; bool forced = false;
      if (t < W_VIS) {
#pragma unroll
        for (int o = 0; o < 8; ++o)
          if (loadS(att, o * W_VIS + t, isbf) != 0.0f) b9 |= (1u << o);
      } else {
        int g = t - W_VIS;
        int rep = g >> 3, oo = g & 7;
        forced = (rep == 1 || rep == 2);
        b9 = 0x100u | (forced ? 0u : (1u << oo));
      }
      Aw = b9 | (forced ? 0x200u : 0u) | 0x400u;
      Bw = b9 | (forced ? 0x400u : 0u) | 0x200u;
    }
    mab[t] = Aw | (Bw << 16);
  } else {                                   // vswz dt=2 rows d=40..47: ones / zeros
    int t = id - (SEG_A + SEG_B + SEG_C);
    if (t < SEG_D) {
      int li8 = t & 7; int t2 = t >> 3;
      int q = t2 & 3; t2 >>= 2;
      int ksv = t2 & 1; t2 >>= 1;
      int kt = t2 % 65, h = t2 / 65;
      bf16 val = (li8 == 0) ? (bf16)1.0f : (bf16)0.0f;
      short8 v8 = {val, val, val, val, val, val, val, val};
      long base = (((long)h * 65 + kt) * 6 + ksv * 3 + 2) * 512;
      *(short8*)(vswz + base + (q * 16 + 8 + li8) * 8) = v8;
    }
  }
}

// ---------- fused QKV GEMM -> q (row-major, prescaled), kswz/vswz (MFMA-fragment order) ----------
__global__ __launch_bounds__(256) void gemm_qkv(
    const bf16* __restrict__ A,
    const bf16* __restrict__ Bq, const bf16* __restrict__ Bk, const bf16* __restrict__ Bv,
    bf16* __restrict__ q, bf16* __restrict__ kswz, bf16* __restrict__ vswz) {
  const float qscale = 0.15811388300841898f * 1.4426950408889634f;  // scale*log2(e)
  int m0 = blockIdx.x * 64;
  int ng = blockIdx.y * 64;
  int wsel = ng / 320;
  int n_in = ng % 320;
  const bf16* Bt = wsel == 0 ? Bq : wsel == 1 ? Bk : Bv;
  int wv = threadIdx.x >> 6, lane = threadIdx.x & 63;
  int quad = lane >> 4, li = lane & 15;
  int wm = wv >> 1, wn = wv & 1;
  f32x4 acc[2][2];
#pragma unroll
  for (int a = 0; a < 2; a++)
#pragma unroll
    for (int b = 0; b < 2; b++) acc[a][b] = (f32x4){0.f, 0.f, 0.f, 0.f};
#pragma unroll
  for (int ks = 0; ks < 10; ++ks) {
    short8 af[2], bfrag[2];
#pragma unroll
    for (int mt = 0; mt < 2; ++mt) {
      int r = m0 + wm * 32 + mt * 16 + li;
      r = r < N_TOK ? r : N_TOK - 1;
      af[mt] = *(const short8*)(A + r * QD + ks * 32 + quad * 8);
    }
#pragma unroll
    for (int nt = 0; nt < 2; ++nt) {
      int r = n_in + wn * 32 + nt * 16 + li;
      bfrag[nt] = *(const short8*)(Bt + r * QD + ks * 32 + quad * 8);
    }
#pragma unroll
    for (int mt = 0; mt < 2; ++mt)
#pragma unroll
      for (int nt = 0; nt < 2; ++nt)
        acc[mt][nt] = __builtin_amdgcn_mfma_f32_16x16x32_bf16(af[mt], bfrag[nt], acc[mt][nt], 0, 0, 0);
  }
#pragma unroll
  for (int mt = 0; mt < 2; ++mt)
#pragma unroll
    for (int nt = 0; nt < 2; ++nt)
#pragma unroll
      for (int r = 0; r < 4; ++r) {
        int row = m0 + wm * 32 + mt * 16 + quad * 4 + r;
        if (row >= N_TOK) continue;
        int col = n_in + wn * 32 + nt * 16 + li;
        int h = col / DH, d = col % DH;
        float v = acc[mt][nt][r];
        int ktile = row >> 6, rr = row & 63;
        if (wsel == 0) {
          q[h * (N_TOK * DH) + row * DH + d] = (bf16)(v * qscale);
        } else if (wsel == 1) {              // K fragment order
          int nt2 = rr >> 4, li2 = rr & 15;
          long base = (((long)h * 65 + ktile) * 4 + nt2) * 640;
          if (d < 32) kswz[base + ((d >> 3) * 16 + li2) * 8 + (d & 7)] = (bf16)v;
          else        kswz[base + 512 + li2 * 8 + (d - 32)] = (bf16)v;
        } else {                             // V fragment order
          int ksv = rr >> 5, q2 = (rr >> 3) & 3, j2 = rr & 7;
          int dt2 = d >> 4, li2 = d & 15;
          long base = (((long)h * 65 + ktile) * 6 + ksv * 3 + dt2) * 512;
          vswz[base + (q2 * 16 + li2) * 8 + j2] = (bf16)v;
        }
      }
}

// ---------- split-K flash attention: 32 q-rows/wave, fragment-coalesced K/V ----------
__global__ __launch_bounds__(256, 3) void attn_kernel(
    const bf16* __restrict__ qg, const bf16* __restrict__ kswz, const bf16* __restrict__ vswz,
    const unsigned int* __restrict__ mab,
    float* __restrict__ opart, float* __restrict__ mpart, float* __restrict__ lpart) {
  __shared__ unsigned short pbuf[4][32][68];   // per-wave 32x64 P tile (stride 68: measured 0 conflicts)
  int bid = blockIdx.x;
  int h = bid & 7;
  int sp = (bid >> 3) & 3;
  int qt = bid >> 5;                // 0..32 (128 q-rows per block)
  int kt0 = (sp * 65) >> 2;
  int kt1 = ((sp + 1) * 65) >> 2;
  int wv = threadIdx.x >> 6, lane = threadIdx.x & 63;
  int quad = lane >> 4, li = lane & 15;
  const bf16* qh = qg + h * (N_TOK * DH);
  const bf16* kz = kswz + (long)h * 65 * 4 * 640;
  const bf16* vz = vswz + (long)h * 65 * 6 * 512;

  int qrow_base = qt * 128 + wv * 32;
  short8 qa0[2], qa1[2];
#pragma unroll
  for (int mt = 0; mt < 2; ++mt) {
    int qr = qrow_base + mt * 16 + li;
    if (qr > N_TOK - 1) qr = N_TOK - 1;
    qa0[mt] = *(const short8*)(qh + qr * DH + quad * 8);
    qa1[mt] = (quad == 0) ? *(const short8*)(qh + qr * DH + 32) : (short8)(__bf16)0.0f;
  }
  unsigned int aw[2][4];
#pragma unroll
  for (int mt = 0; mt < 2; ++mt)
#pragma unroll
    for (int r = 0; r < 4; ++r)
      aw[mt][r] = mab[qrow_base + mt * 16 + quad * 4 + r] & 0xFFFFu;

  f32x4 o[2][3];
#pragma unroll
  for (int mt = 0; mt < 2; ++mt)
#pragma unroll
    for (int d = 0; d < 3; ++d) o[mt][d] = (f32x4){0.f, 0.f, 0.f, 0.f};
  float mr[2][4] = {{-30000.f, -30000.f, -30000.f, -30000.f},
                    {-30000.f, -30000.f, -30000.f, -30000.f}};
  int dkt = qrow_base >> 6;         // wave's 32 rows live inside this single k-tile

  for (int kt = kt0; kt < kt1; ++kt) {
    const bf16* kb_base = kz + (long)kt * 4 * 640;
    f32x4 s[2][4];
    unsigned int bw[4];
#pragma unroll
    for (int nt = 0; nt < 4; ++nt) {
      bw[nt] = mab[kt * 64 + nt * 16 + li] >> 16;
      short8 kb0 = *(const short8*)(kb_base + nt * 640 + lane * 8);       // coalesced 1KB
      s[0][nt] = __builtin_amdgcn_mfma_f32_16x16x32_bf16(qa0[0], kb0, (f32x4){0.f, 0.f, 0.f, 0.f}, 0, 0, 0);
      s[1][nt] = __builtin_amdgcn_mfma_f32_16x16x32_bf16(qa0[1], kb0, (f32x4){0.f, 0.f, 0.f, 0.f}, 0, 0, 0);
      short8 kb1 = (quad == 0) ? *(const short8*)(kb_base + nt * 640 + 512 + li * 8)
                               : (short8)(__bf16)0.0f;
      s[0][nt] = __builtin_amdgcn_mfma_f32_16x16x32_bf16(qa1[0], kb1, s[0][nt], 0, 0, 0);
      s[1][nt] = __builtin_amdgcn_mfma_f32_16x16x32_bf16(qa1[1], kb1, s[1][nt], 0, 0, 0);
    }
    float t[2][4][4];
    if (kt == dkt) {
#pragma unroll
      for (int mt = 0; mt < 2; ++mt)
#pragma unroll
        for (int nt = 0; nt < 4; ++nt)
#pragma unroll
          for (int r = 0; r < 4; ++r) {
            bool kp = ((aw[mt][r] & bw[nt]) != 0u) ||
                      ((qrow_base + mt * 16 + quad * 4 + r) == (kt * 64 + nt * 16 + li));
            t[mt][nt][r] = kp ? s[mt][nt][r] : -40000.f;
          }
    } else {
#pragma unroll
      for (int mt = 0; mt < 2; ++mt)
#pragma unroll
        for (int nt = 0; nt < 4; ++nt)
#pragma unroll
          for (int r = 0; r < 4; ++r) {
            bool kp = (aw[mt][r] & bw[nt]) != 0u;
            t[mt][nt][r] = kp ? s[mt][nt][r] : -40000.f;
          }
    }
    float mt4[2][4];
#pragma unroll
    for (int mt = 0; mt < 2; ++mt)
#pragma unroll
      for (int r = 0; r < 4; ++r)
        mt4[mt][r] = max16(fmaxf(fmaxf(t[mt][0][r], t[mt][1][r]),
                                 fmaxf(t[mt][2][r], t[mt][3][r])));
    bool grow = false;
#pragma unroll
    for (int mt = 0; mt < 2; ++mt)
#pragma unroll
      for (int r = 0; r < 4; ++r) grow |= (mt4[mt][r] > mr[mt][r]);
    if (__ballot(grow)) {
#pragma unroll
      for (int mt = 0; mt < 2; ++mt)
#pragma unroll
        for (int r = 0; r < 4; ++r) {
          float mn = fmaxf(mr[mt][r], mt4[mt][r]);
          float al = exp2f(mr[mt][r] - mn);
          mr[mt][r] = mn;
#pragma unroll
          for (int d = 0; d < 3; ++d) o[mt][d][r] *= al;
        }
    }
#pragma unroll
    for (int mt = 0; mt < 2; ++mt)
#pragma unroll
      for (int nt = 0; nt < 4; ++nt)
#pragma unroll
        for (int r = 0; r < 4; ++r) {
          float p = exp2f(t[mt][nt][r] - mr[mt][r]);
          bf16 pb = (bf16)p;
          pbuf[wv][mt * 16 + quad * 4 + r][nt * 16 + li] = __builtin_bit_cast(unsigned short, pb);
        }
    // PV: P from own wave's LDS region (compiler inserts lgkmcnt), V coalesced fragments.
    // vswz dt=2 col d=40 is all-ones -> o[mt][2] lane li==8 accumulates l for free.
#pragma unroll
    for (int ksv = 0; ksv < 2; ++ksv) {
      union { short8 v; ushort4 u[2]; } fp[2];
#pragma unroll
      for (int mt = 0; mt < 2; ++mt) {
        fp[mt].u[0] = *(const ushort4*)&pbuf[wv][mt * 16 + li][ksv * 32 + quad * 8];
        fp[mt].u[1] = *(const ushort4*)&pbuf[wv][mt * 16 + li][ksv * 32 + quad * 8 + 4];
      }
#pragma unroll
      for (int dt = 0; dt < 3; ++dt) {
        short8 vb = *(const short8*)(vz + ((long)kt * 6 + ksv * 3 + dt) * 512 + lane * 8);
        o[0][dt] = __builtin_amdgcn_mfma_f32_16x16x32_bf16(fp[0].v, vb, o[0][dt], 0, 0, 0);
        o[1][dt] = __builtin_amdgcn_mfma_f32_16x16x32_bf16(fp[1].v, vb, o[1][dt], 0, 0, 0);
      }
    }
  }
  long pb2 = (long)(sp * 8 + h) * N_SP;
#pragma unroll
  for (int mt = 0; mt < 2; ++mt) {
#pragma unroll
    for (int dt = 0; dt < 3; ++dt) {
      int d = dt * 16 + li;
      if (d < DH) {
#pragma unroll
        for (int r = 0; r < 4; ++r) {
          int row = qrow_base + mt * 16 + quad * 4 + r;
          opart[(pb2 + row) * DH + d] = o[mt][dt][r];
        }
      }
    }
    if (li == 0) {
#pragma unroll
      for (int r = 0; r < 4; ++r)
        mpart[pb2 + qrow_base + mt * 16 + quad * 4 + r] = mr[mt][r];
    }
    if (li == 8) {
#pragma unroll
      for (int r = 0; r < 4; ++r)
        lpart[pb2 + qrow_base + mt * 16 + quad * 4 + r] = o[mt][2][r];
    }
  }
}

// ---------- combine partials across splits ----------
__global__ __launch_bounds__(256) void combine_kernel(
    const float* __restrict__ opart, const float* __restrict__ mpart,
    const float* __restrict__ lpart, bf16* __restrict__ attn) {
  int id = blockIdx.x * 256 + threadIdx.x;
  if (id >= 8 * N_TOK * DH) return;
  int d = id % DH;
  int rw = (id / DH) % N_TOK;
  int h = id / (DH * N_TOK);
  float ms[SPLITS], M = -1e30f;
#pragma unroll
  for (int s = 0; s < SPLITS; ++s) {
    ms[s] = mpart[(long)(s * 8 + h) * N_SP + rw];
    M = fmaxf(M, ms[s]);
  }
  float osum = 0.f, lsum = 0.f;
#pragma unroll
  for (int s = 0; s < SPLITS; ++s) {
    float w = exp2f(ms[s] - M);
    osum += w * opart[((long)(s * 8 + h) * N_SP + rw) * DH + d];
    lsum += w * lpart[(long)(s * 8 + h) * N_SP + rw];
  }
  attn[rw * QD + h * DH + d] = (bf16)(osum / fmaxf(lsum, 1e-30f));
}

// ---------- output projection + bias ----------
__global__ __launch_bounds__(256) void gemm_out(
    const bf16* __restrict__ A, const bf16* __restrict__ Bt,
    const void* __restrict__ bias, void* __restrict__ out,
    const int* __restrict__ flag) {
  bool isbf = flag[0] != 0;
  int m0 = blockIdx.x * 64;
  int n0 = blockIdx.y * 64;
  int wv = threadIdx.x >> 6, lane = threadIdx.x & 63;
  int quad = lane >> 4, li = lane & 15;
  int wm = wv >> 1, wn = wv & 1;
  f32x4 acc[2][2];
#pragma unroll
  for (int a = 0; a < 2; a++)
#pragma unroll
    for (int b = 0; b < 2; b++) acc[a][b] = (f32x4){0.f, 0.f, 0.f, 0.f};
#pragma unroll
  for (int ks = 0; ks < 10; ++ks) {
    short8 af[2], bfrag[2];
#pragma unroll
    for (int mt = 0; mt < 2; ++mt) {
      int r = m0 + wm * 32 + mt * 16 + li;
      r = r < N_TOK ? r : N_TOK - 1;
      af[mt] = *(const short8*)(A + r * QD + ks * 32 + quad * 8);
    }
#pragma unroll
    for (int nt = 0; nt < 2; ++nt) {
      int r = n0 + wn * 32 + nt * 16 + li;
      bfrag[nt] = *(const short8*)(Bt + r * QD + ks * 32 + quad * 8);
    }
#pragma unroll
    for (int mt = 0; mt < 2; ++mt)
#pragma unroll
      for (int nt = 0; nt < 2; ++nt)
        acc[mt][nt] = __builtin_amdgcn_mfma_f32_16x16x32_bf16(af[mt], bfrag[nt], acc[mt][nt], 0, 0, 0);
  }
#pragma unroll
  for (int mt = 0; mt < 2; ++mt)
#pragma unroll
    for (int nt = 0; nt < 2; ++nt)
#pragma unroll
      for (int r = 0; r < 4; ++r) {
        int row = m0 + wm * 32 + mt * 16 + quad * 4 + r;
        if (row >= N_TOK) continue;
        int col = n0 + wn * 32 + nt * 16 + li;
        float val = acc[mt][nt][r] + loadS(bias, col, isbf);
        if (isbf) ((bf16*)out)[row * QD + col] = (bf16)val;
        else      ((float*)out)[row * QD + col] = val;
      }
}

extern "C" void kernel_launch(void* const* d_in, const int* in_sizes, int n_in,
                              void* d_out, int out_size, void* d_ws, size_t ws_size,
                              hipStream_t stream) {
  (void)in_sizes; (void)n_in; (void)out_size; (void)ws_size;
  const void* x   = d_in[0];
  const void* att = d_in[1];
  const void* Wq  = d_in[2];
  const void* Wk  = d_in[3];
  const void* Wv  = d_in[4];
  const void* Wo  = d_in[5];
  const void* bo  = d_in[6];
  char* ws = (char*)d_ws;
  bf16* Wqt = (bf16*)(ws + 0);
  bf16* Wkt = (bf16*)(ws + 204800);
  bf16* Wvt = (bf16*)(ws + 409600);
  bf16* Wot = (bf16*)(ws + 614400);
  unsigned int* mab = (unsigned int*)(ws + 819200);   // 4224*4 = 16896
  bf16* xbf  = (bf16*)(ws + 836096);                  // 2641920
  bf16* qb   = (bf16*)(ws + 3478016);                 // 2641920
  bf16* kswz = (bf16*)(ws + 6119936);                 // 8*65*4*1280 = 2662400
  bf16* vswz = (bf16*)(ws + 8782336);                 // 8*65*6*1024 = 3194880
  bf16* attn = (bf16*)(ws + 11977216);                // 2641920
  int* flag  = (int*)(ws + 14619136);                 // 256
  float* opart = (float*)(ws + 14619392);             // 4*8*4224*40*4 = 21626880
  float* mpart = (float*)(ws + 36246272);             // 540672
  float* lpart = (float*)(ws + 36786944);             // 540672 -> total 37327616

  sniff_kernel<<<1, 256, 0, stream>>>((const unsigned short*)att, flag);
  prep_kernel<<<(SEG_A + SEG_B + SEG_C + SEG_D + 255) / 256, 256, 0, stream>>>(
      x, att, Wq, Wk, Wv, Wo, Wqt, Wkt, Wvt, Wot, xbf, mab, vswz, flag);
  dim3 g1(65, 15);
  gemm_qkv<<<g1, 256, 0, stream>>>(xbf, Wqt, Wkt, Wvt, qb, kswz, vswz);
  attn_kernel<<<33 * SPLITS * 8, 256, 0, stream>>>(qb, kswz, vswz, mab, opart, mpart, lpart);
  combine_kernel<<<(8 * N_TOK * DH + 255) / 256, 256, 0, stream>>>(opart, mpart, lpart, attn);
  dim3 g2(65, 5);
  gemm_out<<<g2, 256, 0, stream>>>(attn, Wot, bo, d_out, flag);
}

// Round 6
// 197.690 us; speedup vs baseline: 1.6643x; 1.3356x over previous
//
#include <hip/hip_runtime.h>

typedef __bf16 bf16;
using short8 = __attribute__((ext_vector_type(8))) __bf16;
using f32x4  = __attribute__((ext_vector_type(4))) float;

#define N_TOK 4128
#define QD    320
#define DH    40
#define W_VIS 4096
#define SPLITS 4
#define N_SP  4224   /* padded row count for partials / mask words */

#if __has_builtin(__builtin_amdgcn_exp2f)
#define EXP2F(x) __builtin_amdgcn_exp2f(x)
#else
#define EXP2F(x) exp2f(x)
#endif

__device__ __forceinline__ float loadS(const void* b, long i, bool isbf) {
  return isbf ? (float)((const bf16*)b)[i] : ((const float*)b)[i];
}

// ---------- dtype sniffer: att_masks is {0,1}; fp32 -> even halfwords all 0 ----------
__global__ __launch_bounds__(256) void sniff_kernel(const unsigned short* att_h, int* flag) {
  __shared__ int s;
  if (threadIdx.x == 0) s = 0;
  __syncthreads();
  int any = 0;
  for (int i = threadIdx.x; i < 4096; i += 256) any |= (att_h[2 * i] != 0);
  if (any) atomicOr(&s, 1);
  __syncthreads();
  if (threadIdx.x == 0) flag[0] = s;
}

// ---------- prep: weight transposes, x->bf16, mask words, V ones-row ----------
#define SEG_A 102400             /* 409600 weight elems / 4 */
#define SEG_B 330240             /* 1320960 x elems / 4 */
#define SEG_C N_SP               /* mask words */
#define SEG_D 33280              /* vswz ones row: 8h*65kt*2ksv*4q*8li */
__global__ __launch_bounds__(256) void prep_kernel(
    const void* __restrict__ x, const void* __restrict__ att,
    const void* __restrict__ Wq, const void* __restrict__ Wk,
    const void* __restrict__ Wv, const void* __restrict__ Wo,
    bf16* __restrict__ Wqt, bf16* __restrict__ Wkt,
    bf16* __restrict__ Wvt, bf16* __restrict__ Wot,
    bf16* __restrict__ xbf, unsigned int* __restrict__ mab,
    bf16* __restrict__ vswz, const int* __restrict__ flag) {
  bool isbf = flag[0] != 0;
  int id = blockIdx.x * 256 + threadIdx.x;
  if (id < SEG_A) {                         // weight transpose, 4 n per thread
    int wsel = id / 25600;
    int r = id % 25600;
    int k = r / 80, n4 = (r % 80) * 4;
    const void* src = wsel == 0 ? Wq : wsel == 1 ? Wk : wsel == 2 ? Wv : Wo;
    bf16* dst       = wsel == 0 ? Wqt : wsel == 1 ? Wkt : wsel == 2 ? Wvt : Wot;
#pragma unroll
    for (int i = 0; i < 4; ++i)
      dst[(n4 + i) * 320 + k] = (bf16)loadS(src, k * 320 + n4 + i, isbf);
  } else if (id < SEG_A + SEG_B) {          // x -> bf16, 4 elems
    int i4 = (id - SEG_A) * 4;
#pragma unroll
    for (int i = 0; i < 4; ++i) xbf[i4 + i] = (bf16)loadS(x, i4 + i, isbf);
  } else if (id < SEG_A + SEG_B + SEG_C) {  // mask words: keep(i,j)=(A[i]&B[j])!=0
    int t = id - (SEG_A + SEG_B);
    unsigned int Aw = 0u, Bw = 0u;
    if (t < N_TOK) {
      unsigned int b9 = 0u; bool forced = false;
      if (t < W_VIS) {
#pragma unroll
        for (int o = 0; o < 8; ++o)
          if (loadS(att, o * W_VIS + t, isbf) != 0.0f) b9 |= (1u << o);
      } else {
        int g = t - W_VIS;
        int rep = g >> 3, oo = g & 7;
        forced = (rep == 1 || rep == 2);
        b9 = 0x100u | (forced ? 0u : (1u << oo));
      }
      Aw = b9 | (forced ? 0x200u : 0u) | 0x400u;
      Bw = b9 | (forced ? 0x400u : 0u) | 0x200u;
    }
    mab[t] = Aw | (Bw << 16);
  } else {                                   // vswz dt=2 rows d=40..47: ones / zeros
    int t = id - (SEG_A + SEG_B + SEG_C);
    if (t < SEG_D) {
      int li8 = t & 7; int t2 = t >> 3;
      int q = t2 & 3; t2 >>= 2;
      int ksv = t2 & 1; t2 >>= 1;
      int kt = t2 % 65, h = t2 / 65;
      bf16 val = (li8 == 0) ? (bf16)1.0f : (bf16)0.0f;
      short8 v8 = {val, val, val, val, val, val, val, val};
      long base = (((long)h * 65 + kt) * 6 + ksv * 3 + 2) * 512;
      *(short8*)(vswz + base + (q * 16 + 8 + li8) * 8) = v8;
    }
  }
}

// ---------- fused QKV GEMM -> q (row-major, prescaled), kswz/vswz (MFMA-fragment order) ----------
__global__ __launch_bounds__(256) void gemm_qkv(
    const bf16* __restrict__ A,
    const bf16* __restrict__ Bq, const bf16* __restrict__ Bk, const bf16* __restrict__ Bv,
    bf16* __restrict__ q, bf16* __restrict__ kswz, bf16* __restrict__ vswz) {
  const float qscale = 0.15811388300841898f * 1.4426950408889634f;  // scale*log2(e)
  int m0 = blockIdx.x * 64;
  int ng = blockIdx.y * 64;
  int wsel = ng / 320;
  int n_in = ng % 320;
  const bf16* Bt = wsel == 0 ? Bq : wsel == 1 ? Bk : Bv;
  int wv = threadIdx.x >> 6, lane = threadIdx.x & 63;
  int quad = lane >> 4, li = lane & 15;
  int wm = wv >> 1, wn = wv & 1;
  f32x4 acc[2][2];
#pragma unroll
  for (int a = 0; a < 2; a++)
#pragma unroll
    for (int b = 0; b < 2; b++) acc[a][b] = (f32x4){0.f, 0.f, 0.f, 0.f};
#pragma unroll
  for (int ks = 0; ks < 10; ++ks) {
    short8 af[2], bfrag[2];
#pragma unroll
    for (int mt = 0; mt < 2; ++mt) {
      int r = m0 + wm * 32 + mt * 16 + li;
      r = r < N_TOK ? r : N_TOK - 1;
      af[mt] = *(const short8*)(A + r * QD + ks * 32 + quad * 8);
    }
#pragma unroll
    for (int nt = 0; nt < 2; ++nt) {
      int r = n_in + wn * 32 + nt * 16 + li;
      bfrag[nt] = *(const short8*)(Bt + r * QD + ks * 32 + quad * 8);
    }
#pragma unroll
    for (int mt = 0; mt < 2; ++mt)
#pragma unroll
      for (int nt = 0; nt < 2; ++nt)
        acc[mt][nt] = __builtin_amdgcn_mfma_f32_16x16x32_bf16(af[mt], bfrag[nt], acc[mt][nt], 0, 0, 0);
  }
#pragma unroll
  for (int mt = 0; mt < 2; ++mt)
#pragma unroll
    for (int nt = 0; nt < 2; ++nt)
#pragma unroll
      for (int r = 0; r < 4; ++r) {
        int row = m0 + wm * 32 + mt * 16 + quad * 4 + r;
        if (row >= N_TOK) continue;
        int col = n_in + wn * 32 + nt * 16 + li;
        int h = col / DH, d = col % DH;
        float v = acc[mt][nt][r];
        int ktile = row >> 6, rr = row & 63;
        if (wsel == 0) {
          q[h * (N_TOK * DH) + row * DH + d] = (bf16)(v * qscale);
        } else if (wsel == 1) {              // K fragment order
          int nt2 = rr >> 4, li2 = rr & 15;
          long base = (((long)h * 65 + ktile) * 4 + nt2) * 640;
          if (d < 32) kswz[base + ((d >> 3) * 16 + li2) * 8 + (d & 7)] = (bf16)v;
          else        kswz[base + 512 + li2 * 8 + (d - 32)] = (bf16)v;
        } else {                             // V fragment order
          int ksv = rr >> 5, q2 = (rr >> 3) & 3, j2 = rr & 7;
          int dt2 = d >> 4, li2 = d & 15;
          long base = (((long)h * 65 + ktile) * 6 + ksv * 3 + dt2) * 512;
          vswz[base + (q2 * 16 + li2) * 8 + j2] = (bf16)v;
        }
      }
}

// ---------- split-K flash attention: static-max softmax (M=8 folded into MFMA C) ----------
__global__ __launch_bounds__(256) void attn_kernel(
    const bf16* __restrict__ qg, const bf16* __restrict__ kswz, const bf16* __restrict__ vswz,
    const unsigned int* __restrict__ mab,
    float* __restrict__ opart, float* __restrict__ lpart) {
  __shared__ unsigned short pbuf[4][16][68];   // per-wave 16x64 P tile (stride 68: 0 conflicts)
  int bid = blockIdx.x;
  int h = bid & 7;
  int sp = (bid >> 3) & 3;
  int qt = bid >> 5;                // 0..64
  int kt0 = (sp * 65) >> 2;
  int kt1 = ((sp + 1) * 65) >> 2;
  int wv = threadIdx.x >> 6, lane = threadIdx.x & 63;
  int quad = lane >> 4, li = lane & 15;
  const bf16* qh = qg + h * (N_TOK * DH);
  const bf16* kz = kswz + (long)h * 65 * 4 * 640;
  const bf16* vz = vswz + (long)h * 65 * 6 * 512;

  int qrow_base = qt * 64 + wv * 16;
  int qr = qrow_base + li; if (qr > N_TOK - 1) qr = N_TOK - 1;
  short8 qa0 = *(const short8*)(qh + qr * DH + quad * 8);
  short8 qa1 = (quad == 0) ? *(const short8*)(qh + qr * DH + 32) : (short8)(__bf16)0.0f;

  unsigned int aw[4]; int qi[4];
#pragma unroll
  for (int r = 0; r < 4; ++r) {
    qi[r] = qrow_base + quad * 4 + r;
    aw[r] = mab[qi[r]] & 0xFFFFu;
  }

  f32x4 o[3];
#pragma unroll
  for (int d = 0; d < 3; ++d) o[d] = (f32x4){0.f, 0.f, 0.f, 0.f};
  const f32x4 cm8 = (f32x4){-8.f, -8.f, -8.f, -8.f};   // static softmax shift
  int dkt = qrow_base >> 6;

  for (int kt = kt0; kt < kt1; ++kt) {
    const bf16* kb_base = kz + (long)kt * 4 * 640;
    f32x4 s[4];
    unsigned int bw[4];
#pragma unroll
    for (int nt = 0; nt < 4; ++nt) {
      bw[nt] = mab[kt * 64 + nt * 16 + li] >> 16;
      short8 kb0 = *(const short8*)(kb_base + nt * 640 + lane * 8);       // coalesced 1KB
      s[nt] = __builtin_amdgcn_mfma_f32_16x16x32_bf16(qa0, kb0, cm8, 0, 0, 0);
      short8 kb1 = (quad == 0) ? *(const short8*)(kb_base + nt * 640 + 512 + li * 8)
                               : (short8)(__bf16)0.0f;
      s[nt] = __builtin_amdgcn_mfma_f32_16x16x32_bf16(qa1, kb1, s[nt], 0, 0, 0);
    }
    // hoist V fragments (independent of P) so their latency hides under exp phase
    short8 vb[2][3];
#pragma unroll
    for (int ksv = 0; ksv < 2; ++ksv)
#pragma unroll
      for (int dt = 0; dt < 3; ++dt)
        vb[ksv][dt] = *(const short8*)(vz + ((long)kt * 6 + ksv * 3 + dt) * 512 + lane * 8);
    // mask -> exp2 (native) -> truncation-pack bf16 -> LDS
    if (kt == dkt) {
#pragma unroll
      for (int nt = 0; nt < 4; ++nt)
#pragma unroll
        for (int r = 0; r < 4; ++r) {
          bool kp = ((aw[r] & bw[nt]) != 0u) || (qi[r] == (kt * 64 + nt * 16 + li));
          float p = EXP2F(kp ? s[nt][r] : -1e5f);
          pbuf[wv][quad * 4 + r][nt * 16 + li] =
              (unsigned short)(__builtin_bit_cast(unsigned int, p) >> 16);
        }
    } else {
#pragma unroll
      for (int nt = 0; nt < 4; ++nt)
#pragma unroll
        for (int r = 0; r < 4; ++r) {
          bool kp = (aw[r] & bw[nt]) != 0u;
          float p = EXP2F(kp ? s[nt][r] : -1e5f);
          pbuf[wv][quad * 4 + r][nt * 16 + li] =
              (unsigned short)(__builtin_bit_cast(unsigned int, p) >> 16);
        }
    }
    // PV: P (A-layout, own wave's LDS region; compiler inserts lgkmcnt) x V fragments.
    // vswz dt=2 col d=40 is all-ones -> o[2] lane li==8 accumulates l for free.
#pragma unroll
    for (int ksv = 0; ksv < 2; ++ksv) {
      union { short8 v; ushort4 u[2]; } fp;
      fp.u[0] = *(const ushort4*)&pbuf[wv][li][ksv * 32 + quad * 8];
      fp.u[1] = *(const ushort4*)&pbuf[wv][li][ksv * 32 + quad * 8 + 4];
#pragma unroll
      for (int dt = 0; dt < 3; ++dt)
        o[dt] = __builtin_amdgcn_mfma_f32_16x16x32_bf16(fp.v, vb[ksv][dt], o[dt], 0, 0, 0);
    }
  }
  long pb2 = (long)(sp * 8 + h) * N_SP;
#pragma unroll
  for (int dt = 0; dt < 3; ++dt) {
    int d = dt * 16 + li;
    if (d < DH) {
#pragma unroll
      for (int r = 0; r < 4; ++r)
        opart[(pb2 + qi[r]) * DH + d] = o[dt][r];
    }
  }
  if (li == 8) {
#pragma unroll
    for (int r = 0; r < 4; ++r) lpart[pb2 + qi[r]] = o[2][r];
  }
}

// ---------- combine partials across splits (equal weights: static max) ----------
__global__ __launch_bounds__(256) void combine_kernel(
    const float* __restrict__ opart, const float* __restrict__ lpart,
    bf16* __restrict__ attn) {
  int id = blockIdx.x * 256 + threadIdx.x;
  if (id >= 8 * N_TOK * DH) return;
  int d = id % DH;
  int rw = (id / DH) % N_TOK;
  int h = id / (DH * N_TOK);
  float osum = 0.f, lsum = 0.f;
#pragma unroll
  for (int s = 0; s < SPLITS; ++s) {
    osum += opart[((long)(s * 8 + h) * N_SP + rw) * DH + d];
    lsum += lpart[(long)(s * 8 + h) * N_SP + rw];
  }
  attn[rw * QD + h * DH + d] = (bf16)(osum / fmaxf(lsum, 1e-30f));
}

// ---------- output projection + bias ----------
__global__ __launch_bounds__(256) void gemm_out(
    const bf16* __restrict__ A, const bf16* __restrict__ Bt,
    const void* __restrict__ bias, void* __restrict__ out,
    const int* __restrict__ flag) {
  bool isbf = flag[0] != 0;
  int m0 = blockIdx.x * 64;
  int n0 = blockIdx.y * 64;
  int wv = threadIdx.x >> 6, lane = threadIdx.x & 63;
  int quad = lane >> 4, li = lane & 15;
  int wm = wv >> 1, wn = wv & 1;
  f32x4 acc[2][2];
#pragma unroll
  for (int a = 0; a < 2; a++)
#pragma unroll
    for (int b = 0; b < 2; b++) acc[a][b] = (f32x4){0.f, 0.f, 0.f, 0.f};
#pragma unroll
  for (int ks = 0; ks < 10; ++ks) {
    short8 af[2], bfrag[2];
#pragma unroll
    for (int mt = 0; mt < 2; ++mt) {
      int r = m0 + wm * 32 + mt * 16 + li;
      r = r < N_TOK ? r : N_TOK - 1;
      af[mt] = *(const short8*)(A + r * QD + ks * 32 + quad * 8);
    }
#pragma unroll
    for (int nt = 0; nt < 2; ++nt) {
      int r = n0 + wn * 32 + nt * 16 + li;
      bfrag[nt] = *(const short8*)(Bt + r * QD + ks * 32 + quad * 8);
    }
#pragma unroll
    for (int mt = 0; mt < 2; ++mt)
#pragma unroll
      for (int nt = 0; nt < 2; ++nt)
        acc[mt][nt] = __builtin_amdgcn_mfma_f32_16x16x32_bf16(af[mt], bfrag[nt], acc[mt][nt], 0, 0, 0);
  }
#pragma unroll
  for (int mt = 0; mt < 2; ++mt)
#pragma unroll
    for (int nt = 0; nt < 2; ++nt)
#pragma unroll
      for (int r = 0; r < 4; ++r) {
        int row = m0 + wm * 32 + mt * 16 + quad * 4 + r;
        if (row >= N_TOK) continue;
        int col = n0 + wn * 32 + nt * 16 + li;
        float val = acc[mt][nt][r] + loadS(bias, col, isbf);
        if (isbf) ((bf16*)out)[row * QD + col] = (bf16)val;
        else      ((float*)out)[row * QD + col] = val;
      }
}

extern "C" void kernel_launch(void* const* d_in, const int* in_sizes, int n_in,
                              void* d_out, int out_size, void* d_ws, size_t ws_size,
                              hipStream_t stream) {
  (void)in_sizes; (void)n_in; (void)out_size; (void)ws_size;
  const void* x   = d_in[0];
  const void* att = d_in[1];
  const void* Wq  = d_in[2];
  const void* Wk  = d_in[3];
  const void* Wv  = d_in[4];
  const void* Wo  = d_in[5];
  const void* bo  = d_in[6];
  char* ws = (char*)d_ws;
  bf16* Wqt = (bf16*)(ws + 0);
  bf16* Wkt = (bf16*)(ws + 204800);
  bf16* Wvt = (bf16*)(ws + 409600);
  bf16* Wot = (bf16*)(ws + 614400);
  unsigned int* mab = (unsigned int*)(ws + 819200);   // 4224*4 = 16896
  bf16* xbf  = (bf16*)(ws + 836096);                  // 2641920
  bf16* qb   = (bf16*)(ws + 3478016);                 // 2641920
  bf16* kswz = (bf16*)(ws + 6119936);                 // 8*65*4*1280 = 2662400
  bf16* vswz = (bf16*)(ws + 8782336);                 // 8*65*6*1024 = 3194880
  bf16* attn = (bf16*)(ws + 11977216);                // 2641920
  int* flag  = (int*)(ws + 14619136);                 // 256
  float* opart = (float*)(ws + 14619392);             // 4*8*4224*40*4 = 21626880
  float* lpart = (float*)(ws + 36246272);             // 540672 -> total 36786944

  sniff_kernel<<<1, 256, 0, stream>>>((const unsigned short*)att, flag);
  prep_kernel<<<(SEG_A + SEG_B + SEG_C + SEG_D + 255) / 256, 256, 0, stream>>>(
      x, att, Wq, Wk, Wv, Wo, Wqt, Wkt, Wvt, Wot, xbf, mab, vswz, flag);
  dim3 g1(65, 15);
  gemm_qkv<<<g1, 256, 0, stream>>>(xbf, Wqt, Wkt, Wvt, qb, kswz, vswz);
  attn_kernel<<<65 * SPLITS * 8, 256, 0, stream>>>(qb, kswz, vswz, mab, opart, lpart);
  combine_kernel<<<(8 * N_TOK * DH + 255) / 256, 256, 0, stream>>>(opart, lpart, attn);
  dim3 g2(65, 5);
  gemm_out<<<g2, 256, 0, stream>>>(attn, Wot, bo, d_out, flag);
}